// Round 1
// baseline (544.670 us; speedup 1.0000x reference)
//
#include <hip/hip_runtime.h>
#include <hip/hip_bf16.h>

#define B_ 2
#define S_ 2048
#define D_ 1024
#define H_ 16
#define FF_ 4096
#define M_ (B_*S_)   // 4096

using u16 = unsigned short;
typedef __attribute__((ext_vector_type(8))) short short8;
typedef __attribute__((ext_vector_type(4))) float f32x4;
typedef __attribute__((ext_vector_type(4))) unsigned short u16x4;

static __device__ __forceinline__ u16 f2bf(float f) {
  __hip_bfloat16 h = __float2bfloat16(f);
  return *reinterpret_cast<u16*>(&h);
}
static __device__ __forceinline__ float bf2f(u16 u) {
  __hip_bfloat16 h; *reinterpret_cast<u16*>(&h) = u;
  return __bfloat162float(h);
}

#define GLDS(gp, lp) __builtin_amdgcn_global_load_lds( \
    (const __attribute__((address_space(1))) void*)(gp), \
    (__attribute__((address_space(3))) void*)(lp), 16, 0, 0)

// ---------------- fp32 -> bf16 conversion ----------------
__global__ __launch_bounds__(256) void conv_f32_bf16(
    const float* __restrict__ src, u16* __restrict__ dst, int n4) {
  int i = blockIdx.x * 256 + threadIdx.x;
  if (i < n4) {
    float4 v = reinterpret_cast<const float4*>(src)[i];
    u16x4 o;
    o.x = f2bf(v.x); o.y = f2bf(v.y); o.z = f2bf(v.z); o.w = f2bf(v.w);
    reinterpret_cast<u16x4*>(dst)[i] = o;
  }
}

// ---------------- LayerNorm (non-parametric), fp32 in -> bf16 out ----------------
__global__ __launch_bounds__(256) void ln_rows(
    const float* __restrict__ x, u16* __restrict__ out) {
  int row = blockIdx.x;
  int t = threadIdx.x;
  float4 v = reinterpret_cast<const float4*>(x + (size_t)row * D_)[t];
  float s  = v.x + v.y + v.z + v.w;
  float ss = v.x*v.x + v.y*v.y + v.z*v.z + v.w*v.w;
  #pragma unroll
  for (int off = 1; off < 64; off <<= 1) {
    s  += __shfl_xor(s,  off, 64);
    ss += __shfl_xor(ss, off, 64);
  }
  __shared__ float rs[4], rss[4];
  int wid = t >> 6;
  if ((t & 63) == 0) { rs[wid] = s; rss[wid] = ss; }
  __syncthreads();
  s  = rs[0] + rs[1] + rs[2] + rs[3];
  ss = rss[0] + rss[1] + rss[2] + rss[3];
  float mean = s * (1.0f / D_);
  float var  = ss * (1.0f / D_) - mean * mean;
  float r = rsqrtf(var + 1e-5f);
  u16x4 o;
  o.x = f2bf((v.x - mean) * r);
  o.y = f2bf((v.y - mean) * r);
  o.z = f2bf((v.z - mean) * r);
  o.w = f2bf((v.w - mean) * r);
  reinterpret_cast<u16x4*>(out + (size_t)row * D_)[t] = o;
}

// ---------------- BT GEMM: C[M,N] = A[M,K] * W[N,K]^T ----------------
// MODE 0: store bf16
// MODE 1: store fp32 = acc + res[M,N]
// MODE 2: store bf16 = silu(acc)
// MODE 3: store bf16 = acc * aux[M,N] (bf16 aux)
template<int MODE>
__global__ __launch_bounds__(256) void gemm_bt(
    const u16* __restrict__ A, const u16* __restrict__ W,
    void* __restrict__ C, const u16* __restrict__ aux,
    const float* __restrict__ res, int M, int N, int K)
{
  __shared__ u16 As[128 * 64];
  __shared__ u16 Bs[128 * 64];
  const int tid = threadIdx.x;
  const int wid = tid >> 6, lane = tid & 63;
  const int g = lane >> 4, c = lane & 15;
  const int bm = blockIdx.y, bn = blockIdx.x;
  const int wm = wid >> 1, wn = wid & 1;

  f32x4 acc[4][4];
  #pragma unroll
  for (int i = 0; i < 4; i++)
    #pragma unroll
    for (int j = 0; j < 4; j++) acc[i][j] = {0.f, 0.f, 0.f, 0.f};

  for (int k0 = 0; k0 < K; k0 += 64) {
    #pragma unroll
    for (int i = 0; i < 4; i++) {
      int loff = (wid * 4 + i) * 1024 + lane * 16;  // byte offset in 16KB tile
      int row  = loff >> 7;                          // /128 (64 bf16 per row)
      int colb = loff & 127;
      const char* ga = (const char*)A + ((size_t)(bm * 128 + row) * K + k0) * 2 + colb;
      GLDS(ga, (char*)As + loff);
      const char* gb = (const char*)W + ((size_t)(bn * 128 + row) * K + k0) * 2 + colb;
      GLDS(gb, (char*)Bs + loff);
    }
    __syncthreads();

    short8 af[2][4], bfr[2][4];
    #pragma unroll
    for (int ks = 0; ks < 2; ks++)
      #pragma unroll
      for (int m = 0; m < 4; m++)
        af[ks][m] = *reinterpret_cast<const short8*>(
            &As[(wm * 64 + m * 16 + c) * 64 + ks * 32 + g * 8]);
    #pragma unroll
    for (int ks = 0; ks < 2; ks++)
      #pragma unroll
      for (int n = 0; n < 4; n++)
        bfr[ks][n] = *reinterpret_cast<const short8*>(
            &Bs[(wn * 64 + n * 16 + c) * 64 + ks * 32 + g * 8]);
    #pragma unroll
    for (int m = 0; m < 4; m++)
      #pragma unroll
      for (int n = 0; n < 4; n++) {
        acc[m][n] = __builtin_amdgcn_mfma_f32_16x16x32_bf16(af[0][m], bfr[0][n], acc[m][n], 0, 0, 0);
        acc[m][n] = __builtin_amdgcn_mfma_f32_16x16x32_bf16(af[1][m], bfr[1][n], acc[m][n], 0, 0, 0);
      }
    __syncthreads();
  }

  #pragma unroll
  for (int m = 0; m < 4; m++)
    #pragma unroll
    for (int n = 0; n < 4; n++)
      #pragma unroll
      for (int r = 0; r < 4; r++) {
        int gr = bm * 128 + wm * 64 + m * 16 + g * 4 + r;
        int gc = bn * 128 + wn * 64 + n * 16 + c;
        size_t idx = (size_t)gr * N + gc;
        float v = acc[m][n][r];
        if (MODE == 0) {
          ((u16*)C)[idx] = f2bf(v);
        } else if (MODE == 1) {
          ((float*)C)[idx] = v + res[idx];
        } else if (MODE == 2) {
          ((u16*)C)[idx] = f2bf(v / (1.0f + __expf(-v)));
        } else {
          ((u16*)C)[idx] = f2bf(v * bf2f(aux[idx]));
        }
      }
}

// ---------------- V transpose: qkv v-section [B,S,H*64] -> vT [B*H, 64, S] ----------------
__global__ __launch_bounds__(256) void transpose_v(
    const u16* __restrict__ qkv, u16* __restrict__ vT) {
  __shared__ u16 t[64][66];
  int bh = blockIdx.y;
  int s0 = blockIdx.x * 64;
  int b = bh >> 4, h = bh & 15;
  int tid = threadIdx.x;
  #pragma unroll
  for (int it = 0; it < 2; it++) {
    int idx = it * 256 + tid;
    int row = idx >> 3;          // s within tile
    int cc  = (idx & 7) * 8;     // d chunk
    const u16* src = qkv + ((size_t)(b * S_ + s0 + row)) * 3072 + 2048 + h * 64 + cc;
    short8 v = *reinterpret_cast<const short8*>(src);
    #pragma unroll
    for (int j = 0; j < 8; j++) t[row][cc + j] = (u16)v[j];
  }
  __syncthreads();
  #pragma unroll
  for (int it = 0; it < 2; it++) {
    int idx = it * 256 + tid;
    int d  = idx >> 3;
    int sc = (idx & 7) * 8;
    short8 o;
    #pragma unroll
    for (int j = 0; j < 8; j++) o[j] = (short)t[sc + j][d];
    *reinterpret_cast<short8*>(vT + ((size_t)bh * 64 + d) * S_ + s0 + sc) = o;
  }
}

// ---------------- causal flash attention, 1 wave per 16 q-rows ----------------
__global__ __launch_bounds__(64) void attn_fwd(
    const u16* __restrict__ qkv, const u16* __restrict__ vT, u16* __restrict__ att) {
  const int lane = threadIdx.x;
  const int g = lane >> 4, c = lane & 15;
  const int bh = blockIdx.y, b = bh >> 4, h = bh & 15;
  const int q0 = blockIdx.x * 16;
  const u16* Qb = qkv + ((size_t)b * S_) * 3072 + h * 64;
  const u16* Kb = Qb + 1024;
  const u16* Vt = vT + (size_t)bh * 64 * S_;

  short8 aq[2];
  #pragma unroll
  for (int ks = 0; ks < 2; ks++)
    aq[ks] = *reinterpret_cast<const short8*>(Qb + (size_t)(q0 + c) * 3072 + ks * 32 + g * 8);

  f32x4 o[4];
  #pragma unroll
  for (int np = 0; np < 4; np++) o[np] = {0.f, 0.f, 0.f, 0.f};
  float mrun[4], lsum[4];
  #pragma unroll
  for (int r = 0; r < 4; r++) { mrun[r] = -1e30f; lsum[r] = 0.f; }

  __shared__ u16 Plds[16 * 32];

  const int ktmax = (q0 + 15) >> 5;
  for (int kt = 0; kt <= ktmax; kt++) {
    f32x4 sc0 = {0.f,0.f,0.f,0.f}, sc1 = {0.f,0.f,0.f,0.f};
    #pragma unroll
    for (int ks = 0; ks < 2; ks++) {
      short8 bk0 = *reinterpret_cast<const short8*>(Kb + (size_t)(kt * 32 + c) * 3072 + ks * 32 + g * 8);
      short8 bk1 = *reinterpret_cast<const short8*>(Kb + (size_t)(kt * 32 + 16 + c) * 3072 + ks * 32 + g * 8);
      sc0 = __builtin_amdgcn_mfma_f32_16x16x32_bf16(aq[ks], bk0, sc0, 0, 0, 0);
      sc1 = __builtin_amdgcn_mfma_f32_16x16x32_bf16(aq[ks], bk1, sc1, 0, 0, 0);
    }
    float p0[4], p1[4], rm[4];
    #pragma unroll
    for (int r = 0; r < 4; r++) {
      int qrow = q0 + g * 4 + r;
      p0[r] = (kt * 32 + c      <= qrow) ? sc0[r] * 0.125f : -1e30f;
      p1[r] = (kt * 32 + 16 + c <= qrow) ? sc1[r] * 0.125f : -1e30f;
      rm[r] = fmaxf(p0[r], p1[r]);
    }
    #pragma unroll
    for (int off = 1; off < 16; off <<= 1)
      #pragma unroll
      for (int r = 0; r < 4; r++) rm[r] = fmaxf(rm[r], __shfl_xor(rm[r], off, 64));
    float rsum[4];
    #pragma unroll
    for (int r = 0; r < 4; r++) {
      float mn = fmaxf(mrun[r], rm[r]);
      float alpha = __expf(mrun[r] - mn);
      mrun[r] = mn;
      p0[r] = __expf(p0[r] - mn);
      p1[r] = __expf(p1[r] - mn);
      rsum[r] = p0[r] + p1[r];
      lsum[r] *= alpha;
      #pragma unroll
      for (int np = 0; np < 4; np++) o[np][r] *= alpha;
    }
    #pragma unroll
    for (int off = 1; off < 16; off <<= 1)
      #pragma unroll
      for (int r = 0; r < 4; r++) rsum[r] += __shfl_xor(rsum[r], off, 64);
    #pragma unroll
    for (int r = 0; r < 4; r++) lsum[r] += rsum[r];

    #pragma unroll
    for (int r = 0; r < 4; r++) {
      Plds[(g * 4 + r) * 32 + c]      = f2bf(p0[r]);
      Plds[(g * 4 + r) * 32 + 16 + c] = f2bf(p1[r]);
    }
    __syncthreads();
    short8 pa = *reinterpret_cast<const short8*>(&Plds[c * 32 + g * 8]);
    #pragma unroll
    for (int np = 0; np < 4; np++) {
      short8 bv = *reinterpret_cast<const short8*>(Vt + (size_t)(np * 16 + c) * S_ + kt * 32 + g * 8);
      o[np] = __builtin_amdgcn_mfma_f32_16x16x32_bf16(pa, bv, o[np], 0, 0, 0);
    }
    __syncthreads();
  }

  #pragma unroll
  for (int np = 0; np < 4; np++)
    #pragma unroll
    for (int r = 0; r < 4; r++)
      att[((size_t)(b * S_ + q0 + g * 4 + r)) * D_ + h * 64 + np * 16 + c] =
          f2bf(o[np][r] / lsum[r]);
}

// ---------------- host launch ----------------
extern "C" void kernel_launch(void* const* d_in, const int* in_sizes, int n_in,
                              void* d_out, int out_size, void* d_ws, size_t ws_size,
                              hipStream_t stream) {
  (void)in_sizes; (void)n_in; (void)out_size; (void)ws_size;
  const float* x    = (const float*)d_in[0];
  const float* Wq   = (const float*)d_in[1];
  const float* Wk   = (const float*)d_in[2];
  const float* Wv   = (const float*)d_in[3];
  const float* Wo   = (const float*)d_in[4];
  const float* Wff  = (const float*)d_in[5];
  const float* Wout = (const float*)d_in[6];
  float* out = (float*)d_out;

  char* ws = (char*)d_ws;
  u16*   wqkv = (u16*)(ws);                    // [3072,1024] bf16, 6MB
  u16*   wo   = (u16*)(ws + 6291456);          // [1024,1024], 2MB
  u16*   wff  = (u16*)(ws + 8388608);          // [8192,1024], 16MB
  u16*   wout = (u16*)(ws + 25165824);         // [1024,4096], 8MB
  float* x1   = (float*)(ws + 33554432);       // [4096,1024] f32, 16MB
  char*  P    = ws + 50331648;                 // reuse pool
  u16*   hbuf = (u16*)(P);                     // [4096,1024], 8MB
  u16*   qkv  = (u16*)(P + 8388608);           // [4096,3072], 24MB
  u16*   vT   = (u16*)(P + 33554432);          // [32,64,2048], 8MB
  u16*   att  = (u16*)(P + 41943040);          // [4096,1024], 8MB
  u16*   h2   = (u16*)(P);                     // reuse hbuf slot
  u16*   s1   = (u16*)(P + 8388608);           // [4096,4096], 32MB (over qkv+vT)
  u16*   gbuf = (u16*)(P + 41943040);          // [4096,4096], 32MB (over att)

  // weight conversion fp32 -> bf16
  conv_f32_bf16<<<1024, 256, 0, stream>>>(Wq, wqkv,               262144);
  conv_f32_bf16<<<1024, 256, 0, stream>>>(Wk, wqkv + 1048576,     262144);
  conv_f32_bf16<<<1024, 256, 0, stream>>>(Wv, wqkv + 2097152,     262144);
  conv_f32_bf16<<<1024, 256, 0, stream>>>(Wo, wo,                 262144);
  conv_f32_bf16<<<8192, 256, 0, stream>>>(Wff, wff,               2097152);
  conv_f32_bf16<<<4096, 256, 0, stream>>>(Wout, wout,             1048576);

  // attention sub-block
  ln_rows<<<M_, 256, 0, stream>>>(x, hbuf);
  gemm_bt<0><<<dim3(24, 32), 256, 0, stream>>>(hbuf, wqkv, qkv, nullptr, nullptr, M_, 3072, 1024);
  transpose_v<<<dim3(32, 32), 256, 0, stream>>>(qkv, vT);
  attn_fwd<<<dim3(128, 32), 64, 0, stream>>>(qkv, vT, att);
  gemm_bt<1><<<dim3(8, 32), 256, 0, stream>>>(att, wo, x1, nullptr, x, M_, 1024, 1024);

  // MLP sub-block (SwiGLU)
  ln_rows<<<M_, 256, 0, stream>>>(x1, h2);
  gemm_bt<2><<<dim3(32, 32), 256, 0, stream>>>(h2, wff, s1, nullptr, nullptr, M_, 4096, 1024);
  gemm_bt<3><<<dim3(32, 32), 256, 0, stream>>>(h2, wff + 4194304, gbuf, s1, nullptr, M_, 4096, 1024);
  gemm_bt<1><<<dim3(8, 32), 256, 0, stream>>>(gbuf, wout, out, nullptr, x1, M_, 1024, 4096);
}

// Round 2
// 429.652 us; speedup vs baseline: 1.2677x; 1.2677x over previous
//
#include <hip/hip_runtime.h>
#include <hip/hip_bf16.h>

#define B_ 2
#define S_ 2048
#define D_ 1024
#define H_ 16
#define FF_ 4096
#define M_ (B_*S_)   // 4096

using u16 = unsigned short;
using u32 = unsigned int;
typedef __attribute__((ext_vector_type(8))) short short8;
typedef __attribute__((ext_vector_type(4))) float f32x4;
typedef __attribute__((ext_vector_type(16))) float f32x16;
typedef __attribute__((ext_vector_type(4))) unsigned short u16x4;
typedef __attribute__((ext_vector_type(4))) unsigned int u32x4;

static __device__ __forceinline__ u16 f2bf(float f) {
  __hip_bfloat16 h = __float2bfloat16(f);
  return *reinterpret_cast<u16*>(&h);
}
static __device__ __forceinline__ float bf2f(u16 u) {
  __hip_bfloat16 h; *reinterpret_cast<u16*>(&h) = u;
  return __bfloat162float(h);
}

#define GLDS(gp, lp) __builtin_amdgcn_global_load_lds( \
    (const __attribute__((address_space(1))) void*)(gp), \
    (__attribute__((address_space(3))) void*)(lp), 16, 0, 0)

// ---------------- fp32 -> bf16 conversion ----------------
__global__ __launch_bounds__(256) void conv_f32_bf16(
    const float* __restrict__ src, u16* __restrict__ dst, int n4) {
  int i = blockIdx.x * 256 + threadIdx.x;
  if (i < n4) {
    float4 v = reinterpret_cast<const float4*>(src)[i];
    u16x4 o;
    o.x = f2bf(v.x); o.y = f2bf(v.y); o.z = f2bf(v.z); o.w = f2bf(v.w);
    reinterpret_cast<u16x4*>(dst)[i] = o;
  }
}

// ---------------- LayerNorm (non-parametric), fp32 in -> bf16 out ----------------
__global__ __launch_bounds__(256) void ln_rows(
    const float* __restrict__ x, u16* __restrict__ out) {
  int row = blockIdx.x;
  int t = threadIdx.x;
  float4 v = reinterpret_cast<const float4*>(x + (size_t)row * D_)[t];
  float s  = v.x + v.y + v.z + v.w;
  float ss = v.x*v.x + v.y*v.y + v.z*v.z + v.w*v.w;
  #pragma unroll
  for (int off = 1; off < 64; off <<= 1) {
    s  += __shfl_xor(s,  off, 64);
    ss += __shfl_xor(ss, off, 64);
  }
  __shared__ float rs[4], rss[4];
  int wid = t >> 6;
  if ((t & 63) == 0) { rs[wid] = s; rss[wid] = ss; }
  __syncthreads();
  s  = rs[0] + rs[1] + rs[2] + rs[3];
  ss = rss[0] + rss[1] + rss[2] + rss[3];
  float mean = s * (1.0f / D_);
  float var  = ss * (1.0f / D_) - mean * mean;
  float r = rsqrtf(var + 1e-5f);
  u16x4 o;
  o.x = f2bf((v.x - mean) * r);
  o.y = f2bf((v.y - mean) * r);
  o.z = f2bf((v.z - mean) * r);
  o.w = f2bf((v.w - mean) * r);
  reinterpret_cast<u16x4*>(out + (size_t)row * D_)[t] = o;
}

// ---------------- BT GEMM: C[M,N] = A[M,K] * W[N,K]^T ----------------
template<int MODE>
__global__ __launch_bounds__(256) void gemm_bt(
    const u16* __restrict__ A, const u16* __restrict__ W,
    void* __restrict__ C, const u16* __restrict__ aux,
    const float* __restrict__ res, int M, int N, int K)
{
  __shared__ u16 As[128 * 64];
  __shared__ u16 Bs[128 * 64];
  const int tid = threadIdx.x;
  const int wid = tid >> 6, lane = tid & 63;
  const int g = lane >> 4, c = lane & 15;
  const int bm = blockIdx.y, bn = blockIdx.x;
  const int wm = wid >> 1, wn = wid & 1;

  f32x4 acc[4][4];
  #pragma unroll
  for (int i = 0; i < 4; i++)
    #pragma unroll
    for (int j = 0; j < 4; j++) acc[i][j] = {0.f, 0.f, 0.f, 0.f};

  for (int k0 = 0; k0 < K; k0 += 64) {
    #pragma unroll
    for (int i = 0; i < 4; i++) {
      int loff = (wid * 4 + i) * 1024 + lane * 16;
      int row  = loff >> 7;
      int colb = loff & 127;
      const char* ga = (const char*)A + ((size_t)(bm * 128 + row) * K + k0) * 2 + colb;
      GLDS(ga, (char*)As + loff);
      const char* gb = (const char*)W + ((size_t)(bn * 128 + row) * K + k0) * 2 + colb;
      GLDS(gb, (char*)Bs + loff);
    }
    __syncthreads();

    short8 af[2][4], bfr[2][4];
    #pragma unroll
    for (int ks = 0; ks < 2; ks++)
      #pragma unroll
      for (int m = 0; m < 4; m++)
        af[ks][m] = *reinterpret_cast<const short8*>(
            &As[(wm * 64 + m * 16 + c) * 64 + ks * 32 + g * 8]);
    #pragma unroll
    for (int ks = 0; ks < 2; ks++)
      #pragma unroll
      for (int n = 0; n < 4; n++)
        bfr[ks][n] = *reinterpret_cast<const short8*>(
            &Bs[(wn * 64 + n * 16 + c) * 64 + ks * 32 + g * 8]);
    #pragma unroll
    for (int m = 0; m < 4; m++)
      #pragma unroll
      for (int n = 0; n < 4; n++) {
        acc[m][n] = __builtin_amdgcn_mfma_f32_16x16x32_bf16(af[0][m], bfr[0][n], acc[m][n], 0, 0, 0);
        acc[m][n] = __builtin_amdgcn_mfma_f32_16x16x32_bf16(af[1][m], bfr[1][n], acc[m][n], 0, 0, 0);
      }
    __syncthreads();
  }

  #pragma unroll
  for (int m = 0; m < 4; m++)
    #pragma unroll
    for (int n = 0; n < 4; n++)
      #pragma unroll
      for (int r = 0; r < 4; r++) {
        int gr = bm * 128 + wm * 64 + m * 16 + g * 4 + r;
        int gc = bn * 128 + wn * 64 + n * 16 + c;
        size_t idx = (size_t)gr * N + gc;
        float v = acc[m][n][r];
        if (MODE == 0) {
          ((u16*)C)[idx] = f2bf(v);
        } else if (MODE == 1) {
          ((float*)C)[idx] = v + res[idx];
        } else if (MODE == 2) {
          ((u16*)C)[idx] = f2bf(v / (1.0f + __expf(-v)));
        } else {
          ((u16*)C)[idx] = f2bf(v * bf2f(aux[idx]));
        }
      }
}

// ---------------- V transpose: qkv v-section [B,S,H*64] -> vT [B*H, 64, S] ----------------
__global__ __launch_bounds__(256) void transpose_v(
    const u16* __restrict__ qkv, u16* __restrict__ vT) {
  __shared__ u16 t[64][66];
  int bh = blockIdx.y;
  int s0 = blockIdx.x * 64;
  int b = bh >> 4, h = bh & 15;
  int tid = threadIdx.x;
  #pragma unroll
  for (int it = 0; it < 2; it++) {
    int idx = it * 256 + tid;
    int row = idx >> 3;
    int cc  = (idx & 7) * 8;
    const u16* src = qkv + ((size_t)(b * S_ + s0 + row)) * 3072 + 2048 + h * 64 + cc;
    short8 v = *reinterpret_cast<const short8*>(src);
    #pragma unroll
    for (int j = 0; j < 8; j++) t[row][cc + j] = (u16)v[j];
  }
  __syncthreads();
  #pragma unroll
  for (int it = 0; it < 2; it++) {
    int idx = it * 256 + tid;
    int d  = idx >> 3;
    int sc = (idx & 7) * 8;
    short8 o;
    #pragma unroll
    for (int j = 0; j < 8; j++) o[j] = (short)t[sc + j][d];
    *reinterpret_cast<short8*>(vT + ((size_t)bh * 64 + d) * S_ + s0 + sc) = o;
  }
}

// ---------------- causal flash attention v2 ----------------
// 4 waves/block, 1 wave = 32 q-rows. Swapped QK^T (mfma(K,Q)) in 32x32x16:
// S^T acc: q = lane&31, k in-register: k = 4*half + (r&3) + 8*(r>>2).
// In-register softmax + defer-max (THR=8). P repacked to A-frag via
// pack+shfl_xor(32). O acc: d = lane&31, q = (r&3)+8*(r>>2)+4*half.
__global__ __launch_bounds__(256) void attn_fwd2(
    const u16* __restrict__ qkv, const u16* __restrict__ vT, u16* __restrict__ att) {
  const int lane = threadIdx.x & 63;
  const int wid  = threadIdx.x >> 6;
  const int l31  = lane & 31;
  const int half = lane >> 5;

  int lin  = blockIdx.y * 16 + blockIdx.x;      // 0..511
  int nlin = (lin & 7) * 64 + (lin >> 3);       // bijective XCD swizzle (512%8==0)
  int bh = nlin >> 4;                           // 0..31  (4 heads per XCD chunk)
  int qg = nlin & 15;
  int qt = 63 - (qg * 4 + wid);                 // heavy q-tiles dispatch first
  int b = bh >> 4, hd = bh & 15;
  int q_base = qt * 32;

  const u16* Qb = qkv + ((size_t)(b * S_ + q_base + l31)) * 3072 + hd * 64;
  const u16* Kb = qkv + (size_t)b * S_ * 3072 + 1024 + hd * 64;
  const u16* Vt = vT + (size_t)bh * 64 * S_;

  // Q fragments, scale 1/8 folded in (exact bf16 exponent shift)
  short8 qf[4];
  #pragma unroll
  for (int dt = 0; dt < 4; dt++) {
    short8 v = *reinterpret_cast<const short8*>(Qb + dt * 16 + half * 8);
    #pragma unroll
    for (int j = 0; j < 8; j++) v[j] = (short)f2bf(bf2f((u16)v[j]) * 0.125f);
    qf[dt] = v;
  }

  f32x16 o0, o1;
  #pragma unroll
  for (int r = 0; r < 16; r++) { o0[r] = 0.f; o1[r] = 0.f; }
  float m = -1e30f, lsum = 0.f;

  auto tile = [&](int kt, bool masked) {
    // K fragments (A operand): row = k, 8 d-elems per lane
    short8 kf[4];
    #pragma unroll
    for (int dt = 0; dt < 4; dt++)
      kf[dt] = *reinterpret_cast<const short8*>(
          Kb + (size_t)(kt * 32 + l31) * 3072 + dt * 16 + half * 8);
    f32x16 s;
    #pragma unroll
    for (int r = 0; r < 16; r++) s[r] = 0.f;
    #pragma unroll
    for (int dt = 0; dt < 4; dt++)
      s = __builtin_amdgcn_mfma_f32_32x32x16_bf16(kf[dt], qf[dt], s, 0, 0, 0);

    // V fragments (B operand): col = d (lane&31), 8 s-elems per lane
    short8 vf00 = *reinterpret_cast<const short8*>(Vt + (size_t)l31        * S_ + kt * 32 + half * 8);
    short8 vf01 = *reinterpret_cast<const short8*>(Vt + (size_t)l31        * S_ + kt * 32 + 16 + half * 8);
    short8 vf10 = *reinterpret_cast<const short8*>(Vt + (size_t)(32 + l31) * S_ + kt * 32 + half * 8);
    short8 vf11 = *reinterpret_cast<const short8*>(Vt + (size_t)(32 + l31) * S_ + kt * 32 + 16 + half * 8);

    float p[16];
    #pragma unroll
    for (int r = 0; r < 16; r++) {
      p[r] = s[r];
      if (masked) {
        int kloc = half * 4 + (r & 3) + 8 * (r >> 2);
        if (kloc > l31) p[r] = -1e30f;
      }
    }
    float rm = p[0];
    #pragma unroll
    for (int r = 1; r < 16; r++) rm = fmaxf(rm, p[r]);
    rm = fmaxf(rm, __shfl_xor(rm, 32, 64));

    if (__any(rm > m + 8.0f)) {               // defer-max rescale (T13)
      float mn = fmaxf(m, rm);
      float alpha = __expf(m - mn);
      m = mn;
      lsum *= alpha;
      #pragma unroll
      for (int r = 0; r < 16; r++) {
        int row = (r & 3) + 8 * (r >> 2) + 4 * half;
        float ar = __shfl(alpha, row, 64);
        o0[r] *= ar; o1[r] *= ar;
      }
    }
    float rs = 0.f;
    #pragma unroll
    for (int r = 0; r < 16; r++) { p[r] = __expf(p[r] - m); rs += p[r]; }
    rs += __shfl_xor(rs, 32, 64);
    lsum += rs;

    // pack P to bf16 pairs; exchange halves; assemble A-frags (k ascending)
    u32 pk[8], sp[8];
    #pragma unroll
    for (int i = 0; i < 8; i++) {
      pk[i] = (u32)f2bf(p[2 * i]) | ((u32)f2bf(p[2 * i + 1]) << 16);
      sp[i] = (u32)__shfl_xor((int)pk[i], 32, 64);
    }
    u32x4 a0 = { half ? sp[2] : pk[0], half ? sp[3] : pk[1],
                 half ? pk[2] : sp[0], half ? pk[3] : sp[1] };
    u32x4 a1 = { half ? sp[6] : pk[4], half ? sp[7] : pk[5],
                 half ? pk[6] : sp[4], half ? pk[7] : sp[5] };
    short8 pa0 = *reinterpret_cast<short8*>(&a0);
    short8 pa1 = *reinterpret_cast<short8*>(&a1);

    o0 = __builtin_amdgcn_mfma_f32_32x32x16_bf16(pa0, vf00, o0, 0, 0, 0);
    o0 = __builtin_amdgcn_mfma_f32_32x32x16_bf16(pa1, vf01, o0, 0, 0, 0);
    o1 = __builtin_amdgcn_mfma_f32_32x32x16_bf16(pa0, vf10, o1, 0, 0, 0);
    o1 = __builtin_amdgcn_mfma_f32_32x32x16_bf16(pa1, vf11, o1, 0, 0, 0);
  };

  for (int kt = 0; kt < qt; kt++) tile(kt, false);
  tile(qt, true);

  #pragma unroll
  for (int r = 0; r < 16; r++) {
    int row = (r & 3) + 8 * (r >> 2) + 4 * half;
    float inv = 1.0f / __shfl(lsum, row, 64);
    size_t base = ((size_t)(b * S_ + q_base + row)) * D_ + hd * 64 + l31;
    att[base]      = f2bf(o0[r] * inv);
    att[base + 32] = f2bf(o1[r] * inv);
  }
}

// ---------------- host launch ----------------
extern "C" void kernel_launch(void* const* d_in, const int* in_sizes, int n_in,
                              void* d_out, int out_size, void* d_ws, size_t ws_size,
                              hipStream_t stream) {
  (void)in_sizes; (void)n_in; (void)out_size; (void)ws_size;
  const float* x    = (const float*)d_in[0];
  const float* Wq   = (const float*)d_in[1];
  const float* Wk   = (const float*)d_in[2];
  const float* Wv   = (const float*)d_in[3];
  const float* Wo   = (const float*)d_in[4];
  const float* Wff  = (const float*)d_in[5];
  const float* Wout = (const float*)d_in[6];
  float* out = (float*)d_out;

  char* ws = (char*)d_ws;
  u16*   wqkv = (u16*)(ws);                    // [3072,1024] bf16, 6MB
  u16*   wo   = (u16*)(ws + 6291456);          // [1024,1024], 2MB
  u16*   wff  = (u16*)(ws + 8388608);          // [8192,1024], 16MB
  u16*   wout = (u16*)(ws + 25165824);         // [1024,4096], 8MB
  float* x1   = (float*)(ws + 33554432);       // [4096,1024] f32, 16MB
  char*  P    = ws + 50331648;                 // reuse pool
  u16*   hbuf = (u16*)(P);                     // [4096,1024], 8MB
  u16*   qkv  = (u16*)(P + 8388608);           // [4096,3072], 24MB
  u16*   vT   = (u16*)(P + 33554432);          // [32,64,2048], 8MB
  u16*   att  = (u16*)(P + 41943040);          // [4096,1024], 8MB
  u16*   h2   = (u16*)(P);                     // reuse hbuf slot
  u16*   s1   = (u16*)(P + 8388608);           // [4096,4096], 32MB
  u16*   gbuf = (u16*)(P + 41943040);          // [4096,4096], 32MB

  conv_f32_bf16<<<1024, 256, 0, stream>>>(Wq, wqkv,               262144);
  conv_f32_bf16<<<1024, 256, 0, stream>>>(Wk, wqkv + 1048576,     262144);
  conv_f32_bf16<<<1024, 256, 0, stream>>>(Wv, wqkv + 2097152,     262144);
  conv_f32_bf16<<<1024, 256, 0, stream>>>(Wo, wo,                 262144);
  conv_f32_bf16<<<8192, 256, 0, stream>>>(Wff, wff,               2097152);
  conv_f32_bf16<<<4096, 256, 0, stream>>>(Wout, wout,             1048576);

  ln_rows<<<M_, 256, 0, stream>>>(x, hbuf);
  gemm_bt<0><<<dim3(24, 32), 256, 0, stream>>>(hbuf, wqkv, qkv, nullptr, nullptr, M_, 3072, 1024);
  transpose_v<<<dim3(32, 32), 256, 0, stream>>>(qkv, vT);
  attn_fwd2<<<dim3(16, 32), 256, 0, stream>>>(qkv, vT, att);
  gemm_bt<1><<<dim3(8, 32), 256, 0, stream>>>(att, wo, x1, nullptr, x, M_, 1024, 1024);

  ln_rows<<<M_, 256, 0, stream>>>(x1, h2);
  gemm_bt<2><<<dim3(32, 32), 256, 0, stream>>>(h2, wff, s1, nullptr, nullptr, M_, 4096, 1024);
  gemm_bt<3><<<dim3(32, 32), 256, 0, stream>>>(h2, wff + 4194304, gbuf, s1, nullptr, M_, 4096, 1024);
  gemm_bt<1><<<dim3(8, 32), 256, 0, stream>>>(gbuf, wout, out, nullptr, x1, M_, 1024, 4096);
}

// Round 3
// 380.537 us; speedup vs baseline: 1.4313x; 1.1291x over previous
//
#include <hip/hip_runtime.h>
#include <hip/hip_bf16.h>

#define B_ 2
#define S_ 2048
#define D_ 1024
#define H_ 16
#define FF_ 4096
#define M_ (B_*S_)   // 4096

using u16 = unsigned short;
using u32 = unsigned int;
typedef __attribute__((ext_vector_type(8))) short short8;
typedef __attribute__((ext_vector_type(4))) float f32x4;
typedef __attribute__((ext_vector_type(16))) float f32x16;
typedef __attribute__((ext_vector_type(4))) unsigned short u16x4;
typedef __attribute__((ext_vector_type(4))) unsigned int u32x4;

static __device__ __forceinline__ u16 f2bf(float f) {
  __hip_bfloat16 h = __float2bfloat16(f);
  return *reinterpret_cast<u16*>(&h);
}
static __device__ __forceinline__ float bf2f(u16 u) {
  __hip_bfloat16 h; *reinterpret_cast<u16*>(&h) = u;
  return __bfloat162float(h);
}

#define GLDS(gp, lp) __builtin_amdgcn_global_load_lds( \
    (const __attribute__((address_space(1))) void*)(gp), \
    (__attribute__((address_space(3))) void*)(lp), 16, 0, 0)

#define MFMA16(a, b, c) __builtin_amdgcn_mfma_f32_16x16x32_bf16(a, b, c, 0, 0, 0)
#define BAR() __builtin_amdgcn_s_barrier()
#define LGKM0() asm volatile("s_waitcnt lgkmcnt(0)" ::: "memory")
#define VMC(n) asm volatile("s_waitcnt vmcnt(" #n ")" ::: "memory")

// ---------------- fp32 -> bf16 conversion ----------------
__global__ __launch_bounds__(256) void conv_f32_bf16(
    const float* __restrict__ src, u16* __restrict__ dst, int n4) {
  int i = blockIdx.x * 256 + threadIdx.x;
  if (i < n4) {
    float4 v = reinterpret_cast<const float4*>(src)[i];
    u16x4 o;
    o.x = f2bf(v.x); o.y = f2bf(v.y); o.z = f2bf(v.z); o.w = f2bf(v.w);
    reinterpret_cast<u16x4*>(dst)[i] = o;
  }
}

// ---------------- LayerNorm (non-parametric), fp32 in -> bf16 out ----------------
__global__ __launch_bounds__(256) void ln_rows(
    const float* __restrict__ x, u16* __restrict__ out) {
  int row = blockIdx.x;
  int t = threadIdx.x;
  float4 v = reinterpret_cast<const float4*>(x + (size_t)row * D_)[t];
  float s  = v.x + v.y + v.z + v.w;
  float ss = v.x*v.x + v.y*v.y + v.z*v.z + v.w*v.w;
  #pragma unroll
  for (int off = 1; off < 64; off <<= 1) {
    s  += __shfl_xor(s,  off, 64);
    ss += __shfl_xor(ss, off, 64);
  }
  __shared__ float rs[4], rss[4];
  int wid = t >> 6;
  if ((t & 63) == 0) { rs[wid] = s; rss[wid] = ss; }
  __syncthreads();
  s  = rs[0] + rs[1] + rs[2] + rs[3];
  ss = rss[0] + rss[1] + rss[2] + rss[3];
  float mean = s * (1.0f / D_);
  float var  = ss * (1.0f / D_) - mean * mean;
  float r = rsqrtf(var + 1e-5f);
  u16x4 o;
  o.x = f2bf((v.x - mean) * r);
  o.y = f2bf((v.y - mean) * r);
  o.z = f2bf((v.z - mean) * r);
  o.w = f2bf((v.w - mean) * r);
  reinterpret_cast<u16x4*>(out + (size_t)row * D_)[t] = o;
}

// ---------------- 128x128 BT GEMM (kept for N=1024 shapes) ----------------
// MODE 1: store fp32 = acc + res[M,N]
template<int MODE>
__global__ __launch_bounds__(256) void gemm_bt(
    const u16* __restrict__ A, const u16* __restrict__ W,
    void* __restrict__ C, const u16* __restrict__ aux,
    const float* __restrict__ res, int M, int N, int K)
{
  __shared__ u16 As[128 * 64];
  __shared__ u16 Bs[128 * 64];
  const int tid = threadIdx.x;
  const int wid = tid >> 6, lane = tid & 63;
  const int g = lane >> 4, c = lane & 15;
  const int bm = blockIdx.y, bn = blockIdx.x;
  const int wm = wid >> 1, wn = wid & 1;

  f32x4 acc[4][4];
  #pragma unroll
  for (int i = 0; i < 4; i++)
    #pragma unroll
    for (int j = 0; j < 4; j++) acc[i][j] = {0.f, 0.f, 0.f, 0.f};

  for (int k0 = 0; k0 < K; k0 += 64) {
    #pragma unroll
    for (int i = 0; i < 4; i++) {
      int loff = (wid * 4 + i) * 1024 + lane * 16;
      int row  = loff >> 7;
      int colb = loff & 127;
      const char* ga = (const char*)A + ((size_t)(bm * 128 + row) * K + k0) * 2 + colb;
      GLDS(ga, (char*)As + loff);
      const char* gb = (const char*)W + ((size_t)(bn * 128 + row) * K + k0) * 2 + colb;
      GLDS(gb, (char*)Bs + loff);
    }
    __syncthreads();

    short8 af[2][4], bfr[2][4];
    #pragma unroll
    for (int ks = 0; ks < 2; ks++)
      #pragma unroll
      for (int m = 0; m < 4; m++)
        af[ks][m] = *reinterpret_cast<const short8*>(
            &As[(wm * 64 + m * 16 + c) * 64 + ks * 32 + g * 8]);
    #pragma unroll
    for (int ks = 0; ks < 2; ks++)
      #pragma unroll
      for (int n = 0; n < 4; n++)
        bfr[ks][n] = *reinterpret_cast<const short8*>(
            &Bs[(wn * 64 + n * 16 + c) * 64 + ks * 32 + g * 8]);
    #pragma unroll
    for (int m = 0; m < 4; m++)
      #pragma unroll
      for (int n = 0; n < 4; n++) {
        acc[m][n] = MFMA16(af[0][m], bfr[0][n], acc[m][n]);
        acc[m][n] = MFMA16(af[1][m], bfr[1][n], acc[m][n]);
      }
    __syncthreads();
  }

  #pragma unroll
  for (int m = 0; m < 4; m++)
    #pragma unroll
    for (int n = 0; n < 4; n++)
      #pragma unroll
      for (int r = 0; r < 4; r++) {
        int gr = bm * 128 + wm * 64 + m * 16 + g * 4 + r;
        int gc = bn * 128 + wn * 64 + n * 16 + c;
        size_t idx = (size_t)gr * N + gc;
        float v = acc[m][n][r];
        if (MODE == 0) {
          ((u16*)C)[idx] = f2bf(v);
        } else if (MODE == 1) {
          ((float*)C)[idx] = v + res[idx];
        } else if (MODE == 2) {
          ((u16*)C)[idx] = f2bf(v / (1.0f + __expf(-v)));
        } else {
          ((u16*)C)[idx] = f2bf(v * bf2f(aux[idx]));
        }
      }
}

// ---------------- 256x256 8-phase BT GEMM (T2+T3+T4+T5) ----------------
// C[M,N] = A[M,K] * W[N,K]^T. MODE 0: bf16; MODE 2: silu bf16; MODE 3: acc*aux bf16.
// 8 waves (2Mx4N), BK=64, LDS 128KB = 2buf x 2half x 128x64 x {A,B}.
// XOR swizzle col16 ^= row&7 on both GLDS source and ds_read (T21).
template<int MODE>
__global__ __launch_bounds__(512, 2) void gemm256(
    const u16* __restrict__ A, const u16* __restrict__ W,
    void* __restrict__ C, const u16* __restrict__ aux, int M, int N, int K)
{
  __shared__ u16 lds[65536];  // A: [0,32768), B: [32768,65536)
  const int tid = threadIdx.x;
  const int wid = tid >> 6, lane = tid & 63;
  const int g = lane >> 4, c = lane & 15;
  const int wm = wid >> 2, wn = wid & 3;

  const int gridN = N >> 8;
  int nwg = gridDim.x * gridDim.y;
  int lin = blockIdx.y * gridDim.x + blockIdx.x;
  lin = (lin & 7) * (nwg >> 3) + (lin >> 3);   // bijective XCD swizzle (nwg%8==0)
  const int bm = lin / gridN, bn = lin % gridN;
  const int NT = K >> 6;

  f32x4 acc[8][4];
  #pragma unroll
  for (int i = 0; i < 8; i++)
    #pragma unroll
    for (int j = 0; j < 4; j++) acc[i][j] = {0.f, 0.f, 0.f, 0.f};

  // stage one half-tile (128 rows x 64 cols) of matrix sel at K-tile t
  auto stage = [&](int sel, int t, int half) {
    const u16* src = sel ? W : A;
    const int tilerow = (sel ? bn : bm) * 256 + half * 128;
    const int ldsb = sel * 32768 + (t & 1) * 16384 + half * 8192;
    #pragma unroll
    for (int i = 0; i < 2; i++) {
      int j = i * 512 + tid;
      int row = j >> 3, col16 = j & 7;
      const u16* gp = src + (size_t)(tilerow + row) * K + t * 64 + ((col16 ^ (row & 7)) << 3);
      GLDS(gp, (char*)lds + ldsb * 2 + j * 16);
    }
  };
  auto ldA = [&](short8 (&a)[2][4], int buf, int mh) {
    #pragma unroll
    for (int ks = 0; ks < 2; ks++)
      #pragma unroll
      for (int m = 0; m < 4; m++) {
        int rh = wm * 16 + m * 32 + c;
        a[ks][m] = *reinterpret_cast<const short8*>(
            &lds[buf * 16384 + mh * 8192 + rh * 64 + ((((ks << 2) | g) ^ (rh & 7)) << 3)]);
      }
  };
  auto ldB = [&](short8 (&b)[2][2], int buf, int nh) {
    #pragma unroll
    for (int ks = 0; ks < 2; ks++)
      #pragma unroll
      for (int n = 0; n < 2; n++) {
        int rh = wn * 16 + n * 64 + c;
        b[ks][n] = *reinterpret_cast<const short8*>(
            &lds[32768 + buf * 16384 + nh * 8192 + rh * 64 + ((((ks << 2) | g) ^ (rh & 7)) << 3)]);
      }
  };

#define MFMA_Q(a, b, mb, nb)                                            \
  __builtin_amdgcn_s_setprio(1);                                        \
  _Pragma("unroll")                                                     \
  for (int m = 0; m < 4; m++)                                           \
    _Pragma("unroll")                                                   \
    for (int n = 0; n < 2; n++) {                                       \
      acc[(mb)+m][(nb)+n] = MFMA16(a[0][m], b[0][n], acc[(mb)+m][(nb)+n]); \
      acc[(mb)+m][(nb)+n] = MFMA16(a[1][m], b[1][n], acc[(mb)+m][(nb)+n]); \
    }                                                                   \
  __builtin_amdgcn_s_setprio(0);

  // prologue: t0 all 4 halves, t1 A0,B0 -> vmcnt(4): t0 complete, 2 halves in flight
  stage(0, 0, 0); stage(1, 0, 0); stage(0, 0, 1); stage(1, 0, 1);
  stage(0, 1, 0); stage(1, 1, 0);
  VMC(4);
  BAR();

  for (int t = 0; t < NT; t += 2) {
    const int buf = t & 1;
    short8 a0[2][4], a1[2][4], b0[2][2], b1[2][2];
    // ph1: Q0 = A0 x B0 ; stage A1(t+1)
    ldA(a0, buf, 0); ldB(b0, buf, 0);
    stage(0, t + 1, 1);
    BAR(); LGKM0();
    MFMA_Q(a0, b0, 0, 0);
    BAR();
    // ph2: Q1 = A0 x B1 ; stage B1(t+1)
    ldB(b1, buf, 1);
    stage(1, t + 1, 1);
    BAR(); LGKM0();
    MFMA_Q(a0, b1, 0, 2);
    BAR();
    // ph3: Q2 = A1 x B0 ; stage A0(t+2)
    ldA(a1, buf, 1);
    if (t + 2 < NT) stage(0, t + 2, 0);
    BAR(); LGKM0();
    MFMA_Q(a1, b0, 4, 0);
    BAR();
    // ph4: Q3 = A1 x B1 ; stage B0(t+2) ; counted vmcnt -> t+1 ready
    if (t + 2 < NT) { stage(1, t + 2, 0); VMC(4); } else { VMC(0); }
    BAR(); LGKM0();
    MFMA_Q(a1, b1, 4, 2);
    BAR();
    // ph5-8: K-tile t+1 (buf^1)
    // ph5: Q0 ; stage A1(t+2)
    ldA(a0, buf ^ 1, 0); ldB(b0, buf ^ 1, 0);
    if (t + 2 < NT) stage(0, t + 2, 1);
    BAR(); LGKM0();
    MFMA_Q(a0, b0, 0, 0);
    BAR();
    // ph6: Q1 ; stage B1(t+2)
    ldB(b1, buf ^ 1, 1);
    if (t + 2 < NT) stage(1, t + 2, 1);
    BAR(); LGKM0();
    MFMA_Q(a0, b1, 0, 2);
    BAR();
    // ph7: Q2 ; stage A0(t+3)
    ldA(a1, buf ^ 1, 1);
    if (t + 3 < NT) stage(0, t + 3, 0);
    BAR(); LGKM0();
    MFMA_Q(a1, b0, 4, 0);
    BAR();
    // ph8: Q3 ; stage B0(t+3) ; counted vmcnt -> t+2 ready
    if (t + 3 < NT) { stage(1, t + 3, 0); VMC(4); } else { VMC(0); }
    BAR(); LGKM0();
    MFMA_Q(a1, b1, 4, 2);
    BAR();
  }

  #pragma unroll
  for (int m = 0; m < 8; m++)
    #pragma unroll
    for (int n = 0; n < 4; n++)
      #pragma unroll
      for (int r = 0; r < 4; r++) {
        int gr = bm * 256 + (m >> 2) * 128 + wm * 16 + (m & 3) * 32 + g * 4 + r;
        int gc = bn * 256 + (n >> 1) * 128 + wn * 16 + (n & 1) * 64 + c;
        size_t idx = (size_t)gr * N + gc;
        float v = acc[m][n][r];
        if (MODE == 0) {
          ((u16*)C)[idx] = f2bf(v);
        } else if (MODE == 2) {
          ((u16*)C)[idx] = f2bf(v / (1.0f + __expf(-v)));
        } else {
          ((u16*)C)[idx] = f2bf(v * bf2f(aux[idx]));
        }
      }
#undef MFMA_Q
}

// ---------------- V transpose: qkv v-section -> vT [B*H, 64, S] ----------------
__global__ __launch_bounds__(256) void transpose_v(
    const u16* __restrict__ qkv, u16* __restrict__ vT) {
  __shared__ u16 t[64][66];
  int bh = blockIdx.y;
  int s0 = blockIdx.x * 64;
  int b = bh >> 4, h = bh & 15;
  int tid = threadIdx.x;
  #pragma unroll
  for (int it = 0; it < 2; it++) {
    int idx = it * 256 + tid;
    int row = idx >> 3;
    int cc  = (idx & 7) * 8;
    const u16* src = qkv + ((size_t)(b * S_ + s0 + row)) * 3072 + 2048 + h * 64 + cc;
    short8 v = *reinterpret_cast<const short8*>(src);
    #pragma unroll
    for (int j = 0; j < 8; j++) t[row][cc + j] = (u16)v[j];
  }
  __syncthreads();
  #pragma unroll
  for (int it = 0; it < 2; it++) {
    int idx = it * 256 + tid;
    int d  = idx >> 3;
    int sc = (idx & 7) * 8;
    short8 o;
    #pragma unroll
    for (int j = 0; j < 8; j++) o[j] = (short)t[sc + j][d];
    *reinterpret_cast<short8*>(vT + ((size_t)bh * 64 + d) * S_ + s0 + sc) = o;
  }
}

// ---------------- causal flash attention v3: swapped QK^T + K/V prefetch ----------------
__global__ __launch_bounds__(256) void attn_fwd3(
    const u16* __restrict__ qkv, const u16* __restrict__ vT, u16* __restrict__ att) {
  const int lane = threadIdx.x & 63;
  const int wid  = threadIdx.x >> 6;
  const int l31  = lane & 31;
  const int half = lane >> 5;

  int lin  = blockIdx.y * 16 + blockIdx.x;      // 0..511
  int nlin = (lin & 7) * 64 + (lin >> 3);       // bijective XCD swizzle
  int bh = nlin >> 4;
  int qg = nlin & 15;
  int qt = 63 - (qg * 4 + wid);                 // heavy q-tiles first
  int b = bh >> 4, hd = bh & 15;
  int q_base = qt * 32;

  const u16* Qb = qkv + ((size_t)(b * S_ + q_base + l31)) * 3072 + hd * 64;
  const u16* Kb = qkv + (size_t)b * S_ * 3072 + 1024 + hd * 64;
  const u16* Vt = vT + (size_t)bh * 64 * S_;

  short8 qf[4];
  #pragma unroll
  for (int dt = 0; dt < 4; dt++) {
    short8 v = *reinterpret_cast<const short8*>(Qb + dt * 16 + half * 8);
    #pragma unroll
    for (int j = 0; j < 8; j++) v[j] = (short)f2bf(bf2f((u16)v[j]) * 0.125f);
    qf[dt] = v;
  }

  f32x16 o0, o1;
  #pragma unroll
  for (int r = 0; r < 16; r++) { o0[r] = 0.f; o1[r] = 0.f; }
  float m = -1e30f, lsum = 0.f;

  auto loadK = [&](int kt, short8 (&kf)[4]) {
    #pragma unroll
    for (int dt = 0; dt < 4; dt++)
      kf[dt] = *reinterpret_cast<const short8*>(
          Kb + (size_t)(kt * 32 + l31) * 3072 + dt * 16 + half * 8);
  };
  auto loadV = [&](int kt, short8 (&vf)[4]) {
    vf[0] = *reinterpret_cast<const short8*>(Vt + (size_t)l31        * S_ + kt * 32 + half * 8);
    vf[1] = *reinterpret_cast<const short8*>(Vt + (size_t)l31        * S_ + kt * 32 + 16 + half * 8);
    vf[2] = *reinterpret_cast<const short8*>(Vt + (size_t)(32 + l31) * S_ + kt * 32 + half * 8);
    vf[3] = *reinterpret_cast<const short8*>(Vt + (size_t)(32 + l31) * S_ + kt * 32 + 16 + half * 8);
  };

  short8 kf[4], vf[4];
  loadK(0, kf); loadV(0, vf);

  for (int kt = 0; ; kt++) {
    const bool last = (kt == qt);
    short8 kn[4], vn[4];
    if (!last) { loadK(kt + 1, kn); loadV(kt + 1, vn); }

    f32x16 s;
    #pragma unroll
    for (int r = 0; r < 16; r++) s[r] = 0.f;
    __builtin_amdgcn_s_setprio(1);
    #pragma unroll
    for (int dt = 0; dt < 4; dt++)
      s = __builtin_amdgcn_mfma_f32_32x32x16_bf16(kf[dt], qf[dt], s, 0, 0, 0);
    __builtin_amdgcn_s_setprio(0);

    float p[16];
    #pragma unroll
    for (int r = 0; r < 16; r++) {
      p[r] = s[r];
      if (last) {
        int kloc = half * 4 + (r & 3) + 8 * (r >> 2);
        if (kloc > l31) p[r] = -1e30f;
      }
    }
    float rm = p[0];
    #pragma unroll
    for (int r = 1; r < 16; r++) rm = fmaxf(rm, p[r]);
    rm = fmaxf(rm, __shfl_xor(rm, 32, 64));

    if (__any(rm > m + 8.0f)) {               // defer-max rescale (T13)
      float mn = fmaxf(m, rm);
      float alpha = __expf(m - mn);
      m = mn;
      lsum *= alpha;
      #pragma unroll
      for (int r = 0; r < 16; r++) {
        int row = (r & 3) + 8 * (r >> 2) + 4 * half;
        float ar = __shfl(alpha, row, 64);
        o0[r] *= ar; o1[r] *= ar;
      }
    }
    float rs = 0.f;
    #pragma unroll
    for (int r = 0; r < 16; r++) { p[r] = __expf(p[r] - m); rs += p[r]; }
    rs += __shfl_xor(rs, 32, 64);
    lsum += rs;

    u32 pk[8], sp[8];
    #pragma unroll
    for (int i = 0; i < 8; i++) {
      pk[i] = (u32)f2bf(p[2 * i]) | ((u32)f2bf(p[2 * i + 1]) << 16);
      sp[i] = (u32)__shfl_xor((int)pk[i], 32, 64);
    }
    u32x4 a0 = { half ? sp[2] : pk[0], half ? sp[3] : pk[1],
                 half ? pk[2] : sp[0], half ? pk[3] : sp[1] };
    u32x4 a1 = { half ? sp[6] : pk[4], half ? sp[7] : pk[5],
                 half ? pk[6] : sp[4], half ? pk[7] : sp[5] };
    short8 pa0 = *reinterpret_cast<short8*>(&a0);
    short8 pa1 = *reinterpret_cast<short8*>(&a1);

    __builtin_amdgcn_s_setprio(1);
    o0 = __builtin_amdgcn_mfma_f32_32x32x16_bf16(pa0, vf[0], o0, 0, 0, 0);
    o0 = __builtin_amdgcn_mfma_f32_32x32x16_bf16(pa1, vf[1], o0, 0, 0, 0);
    o1 = __builtin_amdgcn_mfma_f32_32x32x16_bf16(pa0, vf[2], o1, 0, 0, 0);
    o1 = __builtin_amdgcn_mfma_f32_32x32x16_bf16(pa1, vf[3], o1, 0, 0, 0);
    __builtin_amdgcn_s_setprio(0);

    if (last) break;
    #pragma unroll
    for (int i = 0; i < 4; i++) { kf[i] = kn[i]; vf[i] = vn[i]; }
  }

  #pragma unroll
  for (int r = 0; r < 16; r++) {
    int row = (r & 3) + 8 * (r >> 2) + 4 * half;
    float inv = 1.0f / __shfl(lsum, row, 64);
    size_t base = ((size_t)(b * S_ + q_base + row)) * D_ + hd * 64 + l31;
    att[base]      = f2bf(o0[r] * inv);
    att[base + 32] = f2bf(o1[r] * inv);
  }
}

// ---------------- host launch ----------------
extern "C" void kernel_launch(void* const* d_in, const int* in_sizes, int n_in,
                              void* d_out, int out_size, void* d_ws, size_t ws_size,
                              hipStream_t stream) {
  (void)in_sizes; (void)n_in; (void)out_size; (void)ws_size;
  const float* x    = (const float*)d_in[0];
  const float* Wq   = (const float*)d_in[1];
  const float* Wk   = (const float*)d_in[2];
  const float* Wv   = (const float*)d_in[3];
  const float* Wo   = (const float*)d_in[4];
  const float* Wff  = (const float*)d_in[5];
  const float* Wout = (const float*)d_in[6];
  float* out = (float*)d_out;

  char* ws = (char*)d_ws;
  u16*   wqkv = (u16*)(ws);                    // [3072,1024] bf16, 6MB
  u16*   wo   = (u16*)(ws + 6291456);          // [1024,1024], 2MB
  u16*   wff  = (u16*)(ws + 8388608);          // [8192,1024], 16MB
  u16*   wout = (u16*)(ws + 25165824);         // [1024,4096], 8MB
  float* x1   = (float*)(ws + 33554432);       // [4096,1024] f32, 16MB
  char*  P    = ws + 50331648;                 // reuse pool
  u16*   hbuf = (u16*)(P);                     // [4096,1024], 8MB
  u16*   qkv  = (u16*)(P + 8388608);           // [4096,3072], 24MB
  u16*   vT   = (u16*)(P + 33554432);          // [32,64,2048], 8MB
  u16*   att  = (u16*)(P + 41943040);          // [4096,1024], 8MB
  u16*   h2   = (u16*)(P);                     // reuse hbuf slot
  u16*   s1   = (u16*)(P + 8388608);           // [4096,4096], 32MB
  u16*   gbuf = (u16*)(P + 41943040);          // [4096,4096], 32MB

  conv_f32_bf16<<<1024, 256, 0, stream>>>(Wq, wqkv,               262144);
  conv_f32_bf16<<<1024, 256, 0, stream>>>(Wk, wqkv + 1048576,     262144);
  conv_f32_bf16<<<1024, 256, 0, stream>>>(Wv, wqkv + 2097152,     262144);
  conv_f32_bf16<<<1024, 256, 0, stream>>>(Wo, wo,                 262144);
  conv_f32_bf16<<<8192, 256, 0, stream>>>(Wff, wff,               2097152);
  conv_f32_bf16<<<4096, 256, 0, stream>>>(Wout, wout,             1048576);

  ln_rows<<<M_, 256, 0, stream>>>(x, hbuf);
  gemm256<0><<<dim3(12, 16), 512, 0, stream>>>(hbuf, wqkv, qkv, nullptr, M_, 3072, 1024);
  transpose_v<<<dim3(32, 32), 256, 0, stream>>>(qkv, vT);
  attn_fwd3<<<dim3(16, 32), 256, 0, stream>>>(qkv, vT, att);
  gemm_bt<1><<<dim3(8, 32), 256, 0, stream>>>(att, wo, x1, nullptr, x, M_, 1024, 1024);

  ln_rows<<<M_, 256, 0, stream>>>(x1, h2);
  gemm256<2><<<dim3(16, 16), 512, 0, stream>>>(h2, wff, s1, nullptr, M_, 4096, 1024);
  gemm256<3><<<dim3(16, 16), 512, 0, stream>>>(h2, wff + 4194304, gbuf, s1, M_, 4096, 1024);
  gemm_bt<1><<<dim3(8, 32), 256, 0, stream>>>(gbuf, wout, out, nullptr, x1, M_, 1024, 4096);
}